// Round 5
// baseline (168.257 us; speedup 1.0000x reference)
//
#include <hip/hip_runtime.h>
#include <hip/hip_bf16.h>
#include <math.h>

#define B_N 8192
#define D_K 256
#define TILE 128
#define NT 256              // 4 waves, 2x2 wave grid, 64x64 per wave
#define NBLK 64             // B_N / TILE
#define NPAIR 2080          // NBLK*(NBLK+1)/2 upper-triangular tile pairs
#define NCLS 100
#define KEXP 28.8539008177792681f   // 20*log2(e): e^(sim-20) = 2^((dot-1)*KEXP)

typedef __attribute__((ext_vector_type(8))) short short8;
typedef __attribute__((ext_vector_type(4))) float f32x4;

template <bool V> struct BoolC { static constexpr bool value = V; };

__device__ __forceinline__ unsigned short f2bf(float x) {
    unsigned int u = __float_as_uint(x);
    unsigned int r = (u + 0x7FFFu + ((u >> 16) & 1u)) >> 16;
    return (unsigned short)r;
}

// sum over each aligned 16-lane group on the VALU pipe (DPP butterfly+mirrors).
__device__ __forceinline__ float row_sum16(float v) {
    v += __int_as_float(__builtin_amdgcn_update_dpp(0, __float_as_int(v), 0xB1, 0xF, 0xF, true));
    v += __int_as_float(__builtin_amdgcn_update_dpp(0, __float_as_int(v), 0x4E, 0xF, 0xF, true));
    v += __int_as_float(__builtin_amdgcn_update_dpp(0, __float_as_int(v), 0x141, 0xF, 0xF, true));
    v += __int_as_float(__builtin_amdgcn_update_dpp(0, __float_as_int(v), 0x140, 0xF, 0xF, true));
    return v;
}

// -------- Kernel 1: normalize rows -> bf16; block 0 also: label hist + zero accums --------
__global__ void prep_kernel(const float* __restrict__ feat, unsigned short* __restrict__ fnorm,
                            const int* __restrict__ labels, int* __restrict__ cnt,
                            float* __restrict__ gscal, double* __restrict__ accum,
                            unsigned int* __restrict__ done) {
    if (blockIdx.x == 0) {
        __shared__ int h[NCLS];
        int t = threadIdx.x;
        if (t < NCLS) h[t] = 0;
        if (t == 0) {
            gscal[0] = 0.f; gscal[1] = 0.f;
            accum[0] = 0.0; accum[1] = 0.0; accum[2] = 0.0;
            *done = 0u;
        }
        __syncthreads();
        for (int r = t; r < B_N; r += 256) atomicAdd(&h[labels[r]], 1);
        __syncthreads();
        if (t < NCLS) cnt[t] = h[t];
    }
    int wave = threadIdx.x >> 6, lane = threadIdx.x & 63;
    int row = blockIdx.x * 4 + wave;
    float4 v = *(const float4*)(feat + (size_t)row * D_K + lane * 4);
    float ss = v.x * v.x + v.y * v.y + v.z * v.z + v.w * v.w;
    #pragma unroll
    for (int off = 1; off < 64; off <<= 1) ss += __shfl_xor(ss, off);
    float inv = 1.0f / fmaxf(sqrtf(ss), 1e-12f);
    ushort4 o;
    o.x = f2bf(v.x * inv); o.y = f2bf(v.y * inv);
    o.z = f2bf(v.z * inv); o.w = f2bf(v.w * inv);
    *(ushort4*)(fnorm + (size_t)row * D_K + lane * 4) = o;
}

// -------- Kernel 2: upper-triangular sim tiles — BARRIER-FREE K-loop, operands from L2 --------
// Evidence from r0-r4: 50us floor invariant to waves/CU (16 vs 32) and LDS traffic
// (512KB vs 256KB/tile); degrades with more barriers (r4) or spill (r1/r3). Hypothesis:
// the cost is the barrier-delimited chunk structure (syncthreads + vmcnt(0) drain per
// chunk stalls all waves of a block together). This version deletes it: no LDS staging,
// no K-loop barriers. Fragments are loaded straight from global — fnorm is 4MB = one
// XCD's L2, and r0's FETCH (18MB ~ 4.5 re-reads) shows it is L2-resident. Each short8
// frag load = 16 rows x 64B contiguous = 16 L2 lines (~16 L1-cyc): per tile 256 loads
// ~ 4k L1-cyc -> ~33k cyc/CU total ~ 14us of L1 time, below the 50us floor.
// K-loop explicitly 1-deep software-pipelined in registers (loads of ks+1 before MFMAs
// of ks). Diag tiles need no special path (A/B addresses coincide). 4 waves of 64x64:
// acc[4][4]=64 AGPR; live ~150 regs under the 170 budget of (256,3) -> no spill
// (check: WRITE_SIZE must be ~4.2MB). 3 blocks/CU; only 2 barriers per tile (epilogue).
__global__ __launch_bounds__(NT, 3) void main_kernel(
        const unsigned short* __restrict__ fnorm, const int* __restrict__ labels,
        float2* __restrict__ G, float* __restrict__ gscal) {
    int bid = blockIdx.x;
    int b = (int)((sqrtf(8.0f * bid + 1.0f) - 1.0f) * 0.5f);
    while ((b + 1) * (b + 2) / 2 <= bid) ++b;
    while (b * (b + 1) / 2 > bid) --b;
    int a = bid - b * (b + 1) / 2;
    const int row0 = a * TILE, col0 = b * TILE;
    const bool diag = (a == b);

    __shared__ int Ls[2 * TILE];
    __shared__ float2 Rbuf[2 * TILE];           // [wn 0..1][128] row partials
    __shared__ float2 Cbuf[2 * TILE];           // [wm 0..1][128] col partials
    __shared__ int ghs[4];
    __shared__ float gps[4];

    const int tid = threadIdx.x;
    const int lane = tid & 63, wave = tid >> 6;
    const int wm = wave >> 1, wn = wave & 1;    // 2 (row) x 2 (col) waves; each 64x64
    const int l15 = lane & 15, lhi = lane >> 4;
    const short* fn = (const short*)fnorm;

    if (tid < 128) Ls[tid] = labels[row0 + tid];
    else Ls[tid] = labels[col0 + tid - 128];
    if (lane == 0) ghs[wave] = 0;

    // per-lane fragment base addresses (32-bit elem offsets; fnorm is 4MB)
    // A frag mi at ks: fn[arow + mi*16*D_K + ks*32], 16B load per lane
    const int arow = (row0 + wm * 64 + l15) * D_K + lhi * 8;
    const int brow = (col0 + wn * 64 + l15) * D_K + lhi * 8;

    f32x4 acc[4][4];
    #pragma unroll
    for (int i = 0; i < 4; i++)
        #pragma unroll
        for (int j = 0; j < 4; j++) acc[i][j] = {0.f, 0.f, 0.f, 0.f};

    short8 a0[4], b0[4];
    #pragma unroll
    for (int i = 0; i < 4; i++) {
        a0[i] = *(const short8*)(fn + arow + i * 16 * D_K);
        b0[i] = *(const short8*)(fn + brow + i * 16 * D_K);
    }
    #pragma unroll
    for (int ks = 0; ks < 8; ++ks) {
        short8 a1[4], b1[4];
        if (ks < 7) {
            const int ko = (ks + 1) * 32;
            #pragma unroll
            for (int i = 0; i < 4; i++) {
                a1[i] = *(const short8*)(fn + arow + i * 16 * D_K + ko);
                b1[i] = *(const short8*)(fn + brow + i * 16 * D_K + ko);
            }
        }
        #pragma unroll
        for (int mi = 0; mi < 4; mi++)
            #pragma unroll
            for (int ni = 0; ni < 4; ni++)
                acc[mi][ni] = __builtin_amdgcn_mfma_f32_16x16x32_bf16(a0[mi], b0[ni], acc[mi][ni], 0, 0, 0);
        if (ks < 7) {
            #pragma unroll
            for (int i = 0; i < 4; i++) { a0[i] = a1[i]; b0[i] = b1[i]; }
        }
    }
    __syncthreads();   // Ls writes (top of kernel) visible before epilogue reads

    // ---- Epilogue. C/D layout: col = lane&15, row = (lane>>4)*4 + reg ----
    int lc[4], colg[4];
    #pragma unroll
    for (int ni = 0; ni < 4; ni++) {
        int c = wn * 64 + ni * 16 + l15;
        lc[ni] = Ls[128 + c];
        colg[ni] = col0 + c;
    }

    auto body = [&](auto DIAGC) {
        constexpr bool DIAG = decltype(DIAGC)::value;
        float cD[4] = {0.f, 0.f, 0.f, 0.f};
        float gp = 0.f;           // sum of positive-pair dots (this tile)
        bool anyhi = false;       // lane-mask predicate (SALU)

        #pragma unroll
        for (int mi = 0; mi < 4; mi++) {
            #pragma unroll
            for (int reg = 0; reg < 4; reg++) {
                int rloc = wm * 64 + mi * 16 + lhi * 4 + reg;
                int rowg = row0 + rloc;
                int lr = Ls[rloc];
                float d = 0.f;
                #pragma unroll
                for (int ni = 0; ni < 4; ni++) {
                    float dot = acc[mi][ni][reg];
                    float e = __builtin_exp2f((dot - 1.0f) * KEXP);   // e^(sim-20)
                    bool ns = !DIAG || (rowg != colg[ni]);   // off-diag: folds to true
                    float ev = ns ? e : 0.f;
                    d += ev; cD[ni] += ev;
                    bool ps = ns && (lr == lc[ni]);
                    gp += ps ? dot : 0.f;
                    anyhi = anyhi | (ps & (dot > 0.7f));
                }
                d = row_sum16(d);                  // VALU pipe, not LDS pipe
                if (l15 == 0) Rbuf[wn * 128 + rloc] = {d, 0.f};
            }
        }

        if (!DIAG) {
            #pragma unroll
            for (int ni = 0; ni < 4; ni++) {
                cD[ni] += __shfl_xor(cD[ni], 16);
                cD[ni] += __shfl_xor(cD[ni], 32);
            }
            if (lhi == 0) {
                #pragma unroll
                for (int ni = 0; ni < 4; ni++)
                    Cbuf[wm * 128 + wn * 64 + ni * 16 + l15] = {cD[ni], 0.f};
            }
        }

        gp = row_sum16(gp);
        gp += __shfl_xor(gp, 16);
        gp += __shfl_xor(gp, 32);
        if (lane == 0) gps[wave] = gp;

        // ---- Rare path: any high-similarity positive in this wave ----
        if (__any(anyhi)) {
            float cR[4] = {0.f, 0.f, 0.f, 0.f};
            int nhi = 0;
            #pragma unroll
            for (int mi = 0; mi < 4; mi++) {
                #pragma unroll
                for (int reg = 0; reg < 4; reg++) {
                    int rloc = wm * 64 + mi * 16 + lhi * 4 + reg;
                    int rowg = row0 + rloc;
                    int lr = Ls[rloc];
                    float rx = 0.f;
                    #pragma unroll
                    for (int ni = 0; ni < 4; ni++) {
                        float dot = acc[mi][ni][reg];
                        bool ns = !DIAG || (rowg != colg[ni]);
                        bool hi = ns && (lr == lc[ni]) && (dot > 0.7f);
                        float e = hi ? __builtin_exp2f((dot - 1.0f) * KEXP) : 0.f;
                        rx += e; cR[ni] += e; nhi += hi ? 1 : 0;
                    }
                    rx = row_sum16(rx);
                    if (l15 == 0) Rbuf[wn * 128 + rloc].y = rx;
                }
            }
            if (!DIAG) {
                #pragma unroll
                for (int ni = 0; ni < 4; ni++) {
                    cR[ni] += __shfl_xor(cR[ni], 16);
                    cR[ni] += __shfl_xor(cR[ni], 32);
                }
                if (lhi == 0) {
                    #pragma unroll
                    for (int ni = 0; ni < 4; ni++)
                        Cbuf[wm * 128 + wn * 64 + ni * 16 + l15].y = cR[ni];
                }
            }
            #pragma unroll
            for (int off = 1; off < 64; off <<= 1) nhi += __shfl_xor(nhi, off);
            if (lane == 0) ghs[wave] = nhi;
        }
    };
    if (diag) body(BoolC<true>{});
    else body(BoolC<false>{});
    __syncthreads();   // all Rbuf/Cbuf/gps/ghs writes visible

    if (tid < 128) {
        int r = tid;
        float2 a0v = Rbuf[r], a1v = Rbuf[128 + r];
        G[(size_t)b * B_N + row0 + r] = {a0v.x + a1v.x, a0v.y + a1v.y};
    } else if (!diag) {
        int c = tid - 128;
        float2 a0v = Cbuf[c], a1v = Cbuf[128 + c];
        G[(size_t)a * B_N + col0 + c] = {a0v.x + a1v.x, a0v.y + a1v.y};
    }
    if (tid == 0) {
        float w = diag ? 1.0f : 2.0f;   // off-diag tile stands for (i,j) and (j,i)
        float gpt = gps[0] + gps[1] + gps[2] + gps[3];
        atomicAdd(&gscal[0], w * gpt);
        int tot = ghs[0] + ghs[1] + ghs[2] + ghs[3];
        if (tot > 0) atomicAdd(&gscal[1], w * (float)tot);
    }
}

// -------- Kernel 3: per-row reduction over 64 slots + last-block final assembly --------
__global__ void finalize_kernel(const float2* __restrict__ G, const int* __restrict__ labels,
                                const int* __restrict__ cnt, const float* __restrict__ gscal,
                                double* __restrict__ accum, unsigned int* __restrict__ done,
                                float* __restrict__ out) {
    int lane = threadIdx.x & 63, q = threadIdx.x >> 6;   // q = slot quarter
    int r = blockIdx.x * 64 + lane;
    float d = 0.f, rx = 0.f;
    #pragma unroll
    for (int s = 0; s < 16; ++s) {
        float2 g = G[(size_t)(q * 16 + s) * B_N + r];
        d += g.x; rx += g.y;
    }
    __shared__ float2 sh[4][64];
    sh[q][lane] = {d, rx};
    __syncthreads();
    if (threadIdx.x < 64) {
        int rr = blockIdx.x * 64 + threadIdx.x;
        float2 t0 = sh[0][threadIdx.x], t1 = sh[1][threadIdx.x];
        float2 t2 = sh[2][threadIdx.x], t3 = sh[3][threadIdx.x];
        float dd = t0.x + t1.x + t2.x + t3.x;
        float rr2 = t0.y + t1.y + t2.y + t3.y;
        float np = (float)(cnt[labels[rr]] - 1);
        float ld = logf(dd + 1e-12f) + 20.0f;             // log_denom (shift 20)
        double s1 = (double)np * (double)ld;
        double s2 = (double)np;
        double s3 = (rr2 > 0.f) ? (double)logf(rr2 + 1.0f) : 0.0;  // baseline=0: sim_max=20
        #pragma unroll
        for (int off = 1; off < 64; off <<= 1) {
            s1 += __shfl_xor(s1, off);
            s2 += __shfl_xor(s2, off);
            s3 += __shfl_xor(s3, off);
        }
        if (threadIdx.x == 0) {
            atomicAdd(&accum[0], s1);
            atomicAdd(&accum[1], s2);
            atomicAdd(&accum[2], s3);
            __threadfence();
            unsigned int tk = atomicAdd(done, 1u);
            if (tk == gridDim.x - 1) {           // last block assembles the scalar
                double a1 = atomicAdd(&accum[0], 0.0);
                double a2 = atomicAdd(&accum[1], 0.0);
                double a3 = atomicAdd(&accum[2], 0.0);
                double gp = (double)gscal[0];    // sum over ordered pos pairs of dot
                double gh = (double)gscal[1];    // count of high ordered pairs
                double scl = (a2 > 0.0) ? (a1 - 20.0 * gp) / fmax(a2, 1.0) : 0.0;
                double rel = (gh > 0.0) ? a3 / fmax(gh, 1.0) : 0.0;
                double tot = scl + rel;          // BETA = 1.0
                tot = fmin(fmax(tot, 0.0), 10.0);
                out[0] = (float)tot;
            }
        }
    }
}

extern "C" void kernel_launch(void* const* d_in, const int* in_sizes, int n_in,
                              void* d_out, int out_size, void* d_ws, size_t ws_size,
                              hipStream_t stream) {
    const float* feat = (const float*)d_in[0];
    const int* labels = (const int*)d_in[1];
    float* out = (float*)d_out;
    char* ws = (char*)d_ws;

    unsigned short* fnorm = (unsigned short*)(ws);                          // 4 MB
    float2* G          = (float2*)(ws + (size_t)4 * 1024 * 1024);           // 4 MB: [64][8192]
    int*    cnt        = (int*)(ws + (size_t)8 * 1024 * 1024);              // 400 B
    float*  gscal      = (float*)(ws + (size_t)8 * 1024 * 1024 + 1024);     // 8 B
    double* accum      = (double*)(ws + (size_t)8 * 1024 * 1024 + 2048);    // 24 B
    unsigned int* done = (unsigned int*)(ws + (size_t)8 * 1024 * 1024 + 3072); // 4 B

    prep_kernel<<<B_N / 4, 256, 0, stream>>>(feat, fnorm, labels, cnt, gscal, accum, done);
    main_kernel<<<NPAIR, NT, 0, stream>>>(fnorm, labels, G, gscal);
    finalize_kernel<<<B_N / 64, 256, 0, stream>>>(G, labels, cnt, gscal, accum, done, out);
    (void)in_sizes; (void)n_in; (void)out_size; (void)ws_size;
}

// Round 6
// 130.837 us; speedup vs baseline: 1.2860x; 1.2860x over previous
//
#include <hip/hip_runtime.h>
#include <hip/hip_bf16.h>
#include <math.h>

#define B_N 8192
#define D_K 256
#define TILE 128
#define NT 256              // 4 waves, 2x2 wave grid, 64x64 per wave (max LDS reuse)
#define NBLK 64             // B_N / TILE
#define NPAIR 2080          // NBLK*(NBLK+1)/2 upper-triangular tile pairs
#define NCLS 100
#define KEXP 28.8539008177792681f   // 20*log2(e): e^(sim-20) = 2^((dot-1)*KEXP)
#define KCH 64              // K elements per staged chunk (r2-proven 8-slot swizzle)
#define NCHUNK 4            // D_K / KCH

typedef __attribute__((ext_vector_type(8))) short short8;
typedef __attribute__((ext_vector_type(4))) float f32x4;

template <bool V> struct BoolC { static constexpr bool value = V; };

__device__ __forceinline__ unsigned short f2bf(float x) {
    unsigned int u = __float_as_uint(x);
    unsigned int r = (u + 0x7FFFu + ((u >> 16) & 1u)) >> 16;
    return (unsigned short)r;
}

// async global->LDS, 16B per lane: dest = (wave-uniform) lds base + lane*16
__device__ __forceinline__ void gload_lds16(const short* g, short* l) {
    __builtin_amdgcn_global_load_lds(
        (const __attribute__((address_space(1))) void*)g,
        (__attribute__((address_space(3))) void*)l, 16, 0, 0);
}

// sum over each aligned 16-lane group on the VALU pipe (DPP butterfly+mirrors).
__device__ __forceinline__ float row_sum16(float v) {
    v += __int_as_float(__builtin_amdgcn_update_dpp(0, __float_as_int(v), 0xB1, 0xF, 0xF, true));
    v += __int_as_float(__builtin_amdgcn_update_dpp(0, __float_as_int(v), 0x4E, 0xF, 0xF, true));
    v += __int_as_float(__builtin_amdgcn_update_dpp(0, __float_as_int(v), 0x141, 0xF, 0xF, true));
    v += __int_as_float(__builtin_amdgcn_update_dpp(0, __float_as_int(v), 0x140, 0xF, 0xF, true));
    return v;
}

// -------- Kernel 1: normalize rows -> bf16; block 0 also: label hist + zero accums --------
__global__ void prep_kernel(const float* __restrict__ feat, unsigned short* __restrict__ fnorm,
                            const int* __restrict__ labels, int* __restrict__ cnt,
                            float* __restrict__ gscal, double* __restrict__ accum,
                            unsigned int* __restrict__ done) {
    if (blockIdx.x == 0) {
        __shared__ int h[NCLS];
        int t = threadIdx.x;
        if (t < NCLS) h[t] = 0;
        if (t == 0) {
            gscal[0] = 0.f; gscal[1] = 0.f;
            accum[0] = 0.0; accum[1] = 0.0; accum[2] = 0.0;
            *done = 0u;
        }
        __syncthreads();
        for (int r = t; r < B_N; r += 256) atomicAdd(&h[labels[r]], 1);
        __syncthreads();
        if (t < NCLS) cnt[t] = h[t];
    }
    int wave = threadIdx.x >> 6, lane = threadIdx.x & 63;
    int row = blockIdx.x * 4 + wave;
    float4 v = *(const float4*)(feat + (size_t)row * D_K + lane * 4);
    float ss = v.x * v.x + v.y * v.y + v.z * v.z + v.w * v.w;
    #pragma unroll
    for (int off = 1; off < 64; off <<= 1) ss += __shfl_xor(ss, off);
    float inv = 1.0f / fmaxf(sqrtf(ss), 1e-12f);
    ushort4 o;
    o.x = f2bf(v.x * inv); o.y = f2bf(v.y * inv);
    o.z = f2bf(v.z * inv); o.w = f2bf(v.w * inv);
    *(ushort4*)(fnorm + (size_t)row * D_K + lane * 4) = o;
}

// -------- Kernel 2: upper-triangular sim tiles --------
// r4's max-reuse geometry (4 waves of 64x64: LDS reads 256KB/tile = HALF of r2) with r4's
// two poisons removed:
//  (1) spill: r4's bounds(256,3) left ~170 unified regs for ~150 live (acc=64 AGPR) ->
//      allocator spilled 16MB. Here bounds(256,2) = 256-reg budget, ~100 regs of slack.
//      CHECK: WRITE_SIZE must be ~4.16MB.
//  (2) barriers: r4's KCH=32 = 8 drains/tile. Here KCH=64/NCHUNK=4 = r2's proven rhythm.
// Swizzle is r2's byte-identical 8-slot XOR (measured 0 conflicts; frag phase pattern
// unchanged since wave row bases are 0 mod 8). LDS ~69KB -> 2 blocks/CU: partner block
// covers each barrier drain exactly as in r2. MFMA per wave = 128 (deep matrix stream).
// Staging at NT=256: chunk = 128 rows x 128B per panel = 4 shots x 4KB; thread t stages
// phys slot t&7 of row (t>>3)+32*shot; global sub-chunk (t&7)^((t>>3)&7) (shot-invariant
// since 32 = 0 mod 8). LDS dest = t*16B + shot*4KB (linear, DMA-legal).
__global__ __launch_bounds__(NT, 2) void main_kernel(
        const unsigned short* __restrict__ fnorm, const int* __restrict__ labels,
        float2* __restrict__ G, float* __restrict__ gscal) {
    int bid = blockIdx.x;
    int b = (int)((sqrtf(8.0f * bid + 1.0f) - 1.0f) * 0.5f);
    while ((b + 1) * (b + 2) / 2 <= bid) ++b;
    while (b * (b + 1) / 2 > bid) --b;
    int a = bid - b * (b + 1) / 2;
    const int row0 = a * TILE, col0 = b * TILE;
    const bool diag = (a == b);

    __shared__ short As[2][TILE * KCH];         // 2 x 16 KB
    __shared__ short Bs[2][TILE * KCH];         // 2 x 16 KB
    __shared__ int Ls[2 * TILE];
    __shared__ float2 Rbuf[2 * TILE];           // [wn 0..1][128] row partials
    __shared__ float2 Cbuf[2 * TILE];           // [wm 0..1][128] col partials
    __shared__ int ghs[4];
    __shared__ float gps[4];

    const int tid = threadIdx.x;
    const int lane = tid & 63, wave = tid >> 6;
    const int wm = wave >> 1, wn = wave & 1;    // 2 (row) x 2 (col) waves; each 64x64
    const int l15 = lane & 15, lhi = lane >> 4;
    const short* fn = (const short*)fnorm;

    // staging coordinates (r2 mapping, 4 shots): row rs = (tid>>3)+32*shot, slot tid&7,
    // global sub-chunk cs = (tid&7)^((tid>>3)&7); LDS dest linear in tid within each shot
    const int rs = tid >> 3, cs = (tid & 7) ^ (rs & 7);
    const int uds = (tid & ~63) * 8;            // shorts; wave-uniform base, HW adds lane*16B
    const int sgl = rs * D_K + cs * 8;          // global elem offset within panel (shot 0)

    if (tid < 128) Ls[tid] = labels[row0 + tid];
    else Ls[tid] = labels[col0 + tid - 128];
    if (lane == 0) ghs[wave] = 0;

    const int abase = row0 * D_K + sgl;         // 32-bit offsets: fnorm is 4MB
    const int bbase = col0 * D_K + sgl;

    // prologue: stage chunk 0 into buffer 0 (4 shots per panel: 32 rows each)
    #pragma unroll
    for (int s = 0; s < 4; s++) {
        gload_lds16(fn + abase + s * 32 * D_K, &As[0][s * 2048 + uds]);
        if (!diag) gload_lds16(fn + bbase + s * 32 * D_K, &Bs[0][s * 2048 + uds]);
    }

    f32x4 acc[4][4];
    #pragma unroll
    for (int i = 0; i < 4; i++)
        #pragma unroll
        for (int j = 0; j < 4; j++) acc[i][j] = {0.f, 0.f, 0.f, 0.f};

    #pragma unroll
    for (int kc = 0; kc < NCHUNK; ++kc) {
        const int cur = kc & 1;
        __syncthreads();   // drains DMA of chunk kc into buf[cur]; protects buffer reuse
        if (kc < NCHUNK - 1) {              // prefetch chunk kc+1 into the other buffer
            const int nxt = cur ^ 1, ko = (kc + 1) * KCH;
            #pragma unroll
            for (int s = 0; s < 4; s++) {
                gload_lds16(fn + abase + s * 32 * D_K + ko, &As[nxt][s * 2048 + uds]);
                if (!diag) gload_lds16(fn + bbase + s * 32 * D_K + ko, &Bs[nxt][s * 2048 + uds]);
            }
        }
        const short* Asrc = As[cur];
        const short* Bsrc = diag ? As[cur] : Bs[cur];
        #pragma unroll
        for (int ks = 0; ks < 2; ++ks) {
            short8 af[4], bfr[4];
            const int ch8 = ((ks * 4 + lhi) ^ (l15 & 7)) * 8;
            #pragma unroll
            for (int mi = 0; mi < 4; mi++)
                af[mi] = *(const short8*)&Asrc[(wm * 64 + mi * 16 + l15) * KCH + ch8];
            #pragma unroll
            for (int ni = 0; ni < 4; ni++)
                bfr[ni] = *(const short8*)&Bsrc[(wn * 64 + ni * 16 + l15) * KCH + ch8];
            #pragma unroll
            for (int mi = 0; mi < 4; mi++)
                #pragma unroll
                for (int ni = 0; ni < 4; ni++)
                    acc[mi][ni] = __builtin_amdgcn_mfma_f32_16x16x32_bf16(af[mi], bfr[ni], acc[mi][ni], 0, 0, 0);
        }
    }
    __syncthreads();   // all chunk-3 reads done

    // ---- Epilogue (r4-verified). C/D layout: col = lane&15, row = (lane>>4)*4 + reg ----
    int lc[4], colg[4];
    #pragma unroll
    for (int ni = 0; ni < 4; ni++) {
        int c = wn * 64 + ni * 16 + l15;
        lc[ni] = Ls[128 + c];
        colg[ni] = col0 + c;
    }

    auto body = [&](auto DIAGC) {
        constexpr bool DIAG = decltype(DIAGC)::value;
        float cD[4] = {0.f, 0.f, 0.f, 0.f};
        float gp = 0.f;           // sum of positive-pair dots (this tile)
        bool anyhi = false;       // lane-mask predicate (SALU)

        #pragma unroll
        for (int mi = 0; mi < 4; mi++) {
            #pragma unroll
            for (int reg = 0; reg < 4; reg++) {
                int rloc = wm * 64 + mi * 16 + lhi * 4 + reg;
                int rowg = row0 + rloc;
                int lr = Ls[rloc];
                float d = 0.f;
                #pragma unroll
                for (int ni = 0; ni < 4; ni++) {
                    float dot = acc[mi][ni][reg];
                    float e = __builtin_exp2f((dot - 1.0f) * KEXP);   // e^(sim-20)
                    bool ns = !DIAG || (rowg != colg[ni]);   // off-diag: folds to true
                    float ev = ns ? e : 0.f;
                    d += ev; cD[ni] += ev;
                    bool ps = ns && (lr == lc[ni]);
                    gp += ps ? dot : 0.f;
                    anyhi = anyhi | (ps & (dot > 0.7f));
                }
                d = row_sum16(d);                  // VALU pipe, not LDS pipe
                if (l15 == 0) Rbuf[wn * 128 + rloc] = {d, 0.f};
            }
        }

        if (!DIAG) {
            #pragma unroll
            for (int ni = 0; ni < 4; ni++) {
                cD[ni] += __shfl_xor(cD[ni], 16);
                cD[ni] += __shfl_xor(cD[ni], 32);
            }
            if (lhi == 0) {
                #pragma unroll
                for (int ni = 0; ni < 4; ni++)
                    Cbuf[wm * 128 + wn * 64 + ni * 16 + l15] = {cD[ni], 0.f};
            }
        }

        gp = row_sum16(gp);
        gp += __shfl_xor(gp, 16);
        gp += __shfl_xor(gp, 32);
        if (lane == 0) gps[wave] = gp;

        // ---- Rare path: any high-similarity positive in this wave ----
        if (__any(anyhi)) {
            float cR[4] = {0.f, 0.f, 0.f, 0.f};
            int nhi = 0;
            #pragma unroll
            for (int mi = 0; mi < 4; mi++) {
                #pragma unroll
                for (int reg = 0; reg < 4; reg++) {
                    int rloc = wm * 64 + mi * 16 + lhi * 4 + reg;
                    int rowg = row0 + rloc;
                    int lr = Ls[rloc];
                    float rx = 0.f;
                    #pragma unroll
                    for (int ni = 0; ni < 4; ni++) {
                        float dot = acc[mi][ni][reg];
                        bool ns = !DIAG || (rowg != colg[ni]);
                        bool hi = ns && (lr == lc[ni]) && (dot > 0.7f);
                        float e = hi ? __builtin_exp2f((dot - 1.0f) * KEXP) : 0.f;
                        rx += e; cR[ni] += e; nhi += hi ? 1 : 0;
                    }
                    rx = row_sum16(rx);
                    if (l15 == 0) Rbuf[wn * 128 + rloc].y = rx;
                }
            }
            if (!DIAG) {
                #pragma unroll
                for (int ni = 0; ni < 4; ni++) {
                    cR[ni] += __shfl_xor(cR[ni], 16);
                    cR[ni] += __shfl_xor(cR[ni], 32);
                }
                if (lhi == 0) {
                    #pragma unroll
                    for (int ni = 0; ni < 4; ni++)
                        Cbuf[wm * 128 + wn * 64 + ni * 16 + l15].y = cR[ni];
                }
            }
            #pragma unroll
            for (int off = 1; off < 64; off <<= 1) nhi += __shfl_xor(nhi, off);
            if (lane == 0) ghs[wave] = nhi;
        }
    };
    if (diag) body(BoolC<true>{});
    else body(BoolC<false>{});
    __syncthreads();   // all Rbuf/Cbuf/gps/ghs writes visible

    if (tid < 128) {
        int r = tid;
        float2 a0v = Rbuf[r], a1v = Rbuf[128 + r];
        G[(size_t)b * B_N + row0 + r] = {a0v.x + a1v.x, a0v.y + a1v.y};
    } else if (!diag) {
        int c = tid - 128;
        float2 a0v = Cbuf[c], a1v = Cbuf[128 + c];
        G[(size_t)a * B_N + col0 + c] = {a0v.x + a1v.x, a0v.y + a1v.y};
    }
    if (tid == 0) {
        float w = diag ? 1.0f : 2.0f;   // off-diag tile stands for (i,j) and (j,i)
        float gpt = gps[0] + gps[1] + gps[2] + gps[3];
        atomicAdd(&gscal[0], w * gpt);
        int tot = ghs[0] + ghs[1] + ghs[2] + ghs[3];
        if (tot > 0) atomicAdd(&gscal[1], w * (float)tot);
    }
}

// -------- Kernel 3: per-row reduction over 64 slots + last-block final assembly --------
__global__ void finalize_kernel(const float2* __restrict__ G, const int* __restrict__ labels,
                                const int* __restrict__ cnt, const float* __restrict__ gscal,
                                double* __restrict__ accum, unsigned int* __restrict__ done,
                                float* __restrict__ out) {
    int lane = threadIdx.x & 63, q = threadIdx.x >> 6;   // q = slot quarter
    int r = blockIdx.x * 64 + lane;
    float d = 0.f, rx = 0.f;
    #pragma unroll
    for (int s = 0; s < 16; ++s) {
        float2 g = G[(size_t)(q * 16 + s) * B_N + r];
        d += g.x; rx += g.y;
    }
    __shared__ float2 sh[4][64];
    sh[q][lane] = {d, rx};
    __syncthreads();
    if (threadIdx.x < 64) {
        int rr = blockIdx.x * 64 + threadIdx.x;
        float2 t0 = sh[0][threadIdx.x], t1 = sh[1][threadIdx.x];
        float2 t2 = sh[2][threadIdx.x], t3 = sh[3][threadIdx.x];
        float dd = t0.x + t1.x + t2.x + t3.x;
        float rr2 = t0.y + t1.y + t2.y + t3.y;
        float np = (float)(cnt[labels[rr]] - 1);
        float ld = logf(dd + 1e-12f) + 20.0f;             // log_denom (shift 20)
        double s1 = (double)np * (double)ld;
        double s2 = (double)np;
        double s3 = (rr2 > 0.f) ? (double)logf(rr2 + 1.0f) : 0.0;  // baseline=0: sim_max=20
        #pragma unroll
        for (int off = 1; off < 64; off <<= 1) {
            s1 += __shfl_xor(s1, off);
            s2 += __shfl_xor(s2, off);
            s3 += __shfl_xor(s3, off);
        }
        if (threadIdx.x == 0) {
            atomicAdd(&accum[0], s1);
            atomicAdd(&accum[1], s2);
            atomicAdd(&accum[2], s3);
            __threadfence();
            unsigned int tk = atomicAdd(done, 1u);
            if (tk == gridDim.x - 1) {           // last block assembles the scalar
                double a1 = atomicAdd(&accum[0], 0.0);
                double a2 = atomicAdd(&accum[1], 0.0);
                double a3 = atomicAdd(&accum[2], 0.0);
                double gp = (double)gscal[0];    // sum over ordered pos pairs of dot
                double gh = (double)gscal[1];    // count of high ordered pairs
                double scl = (a2 > 0.0) ? (a1 - 20.0 * gp) / fmax(a2, 1.0) : 0.0;
                double rel = (gh > 0.0) ? a3 / fmax(gh, 1.0) : 0.0;
                double tot = scl + rel;          // BETA = 1.0
                tot = fmin(fmax(tot, 0.0), 10.0);
                out[0] = (float)tot;
            }
        }
    }
}

extern "C" void kernel_launch(void* const* d_in, const int* in_sizes, int n_in,
                              void* d_out, int out_size, void* d_ws, size_t ws_size,
                              hipStream_t stream) {
    const float* feat = (const float*)d_in[0];
    const int* labels = (const int*)d_in[1];
    float* out = (float*)d_out;
    char* ws = (char*)d_ws;

    unsigned short* fnorm = (unsigned short*)(ws);                          // 4 MB
    float2* G          = (float2*)(ws + (size_t)4 * 1024 * 1024);           // 4 MB: [64][8192]
    int*    cnt        = (int*)(ws + (size_t)8 * 1024 * 1024);              // 400 B
    float*  gscal      = (float*)(ws + (size_t)8 * 1024 * 1024 + 1024);     // 8 B
    double* accum      = (double*)(ws + (size_t)8 * 1024 * 1024 + 2048);    // 24 B
    unsigned int* done = (unsigned int*)(ws + (size_t)8 * 1024 * 1024 + 3072); // 4 B

    prep_kernel<<<B_N / 4, 256, 0, stream>>>(feat, fnorm, labels, cnt, gscal, accum, done);
    main_kernel<<<NPAIR, NT, 0, stream>>>(fnorm, labels, G, gscal);
    finalize_kernel<<<B_N / 64, 256, 0, stream>>>(G, labels, cnt, gscal, accum, done, out);
    (void)in_sizes; (void)n_in; (void)out_size; (void)ws_size;
}

// Round 7
// 121.649 us; speedup vs baseline: 1.3831x; 1.0755x over previous
//
#include <hip/hip_runtime.h>
#include <hip/hip_bf16.h>
#include <math.h>

#define B_N 8192
#define D_K 256
#define TILE 128
#define NT 512              // 8 waves, 2x4 wave grid, 64x32 per wave (r0-proven, ~60 VGPR)
#define NBLK 64             // B_N / TILE
#define NPAIR 2080          // NBLK*(NBLK+1)/2 upper-triangular tile pairs
#define NCLS 100
#define KEXP 28.8539008177792681f   // 20*log2(e): e^(sim-20) = 2^((dot-1)*KEXP)
#define KCH 32              // K elements per chunk: 8 chunks, 4-buffer counted-vmcnt pipeline
#define NCHUNK 8

typedef __attribute__((ext_vector_type(8))) short short8;
typedef __attribute__((ext_vector_type(4))) float f32x4;

template <bool V> struct BoolC { static constexpr bool value = V; };

__device__ __forceinline__ unsigned short f2bf(float x) {
    unsigned int u = __float_as_uint(x);
    unsigned int r = (u + 0x7FFFu + ((u >> 16) & 1u)) >> 16;
    return (unsigned short)r;
}

// async global->LDS, 16B per lane: dest = (wave-uniform) lds base + lane*16
__device__ __forceinline__ void gload_lds16(const short* g, short* l) {
    __builtin_amdgcn_global_load_lds(
        (const __attribute__((address_space(1))) void*)g,
        (__attribute__((address_space(3))) void*)l, 16, 0, 0);
}

// sum over each aligned 16-lane group on the VALU pipe (DPP butterfly+mirrors).
__device__ __forceinline__ float row_sum16(float v) {
    v += __int_as_float(__builtin_amdgcn_update_dpp(0, __float_as_int(v), 0xB1, 0xF, 0xF, true));
    v += __int_as_float(__builtin_amdgcn_update_dpp(0, __float_as_int(v), 0x4E, 0xF, 0xF, true));
    v += __int_as_float(__builtin_amdgcn_update_dpp(0, __float_as_int(v), 0x141, 0xF, 0xF, true));
    v += __int_as_float(__builtin_amdgcn_update_dpp(0, __float_as_int(v), 0x140, 0xF, 0xF, true));
    return v;
}

// -------- Kernel 1: normalize rows -> bf16; block 0 also: label hist + zero accums --------
__global__ void prep_kernel(const float* __restrict__ feat, unsigned short* __restrict__ fnorm,
                            const int* __restrict__ labels, int* __restrict__ cnt,
                            float* __restrict__ gscal, double* __restrict__ accum,
                            unsigned int* __restrict__ done) {
    if (blockIdx.x == 0) {
        __shared__ int h[NCLS];
        int t = threadIdx.x;
        if (t < NCLS) h[t] = 0;
        if (t == 0) {
            gscal[0] = 0.f; gscal[1] = 0.f;
            accum[0] = 0.0; accum[1] = 0.0; accum[2] = 0.0;
            *done = 0u;
        }
        __syncthreads();
        for (int r = t; r < B_N; r += 256) atomicAdd(&h[labels[r]], 1);
        __syncthreads();
        if (t < NCLS) cnt[t] = h[t];
    }
    int wave = threadIdx.x >> 6, lane = threadIdx.x & 63;
    int row = blockIdx.x * 4 + wave;
    float4 v = *(const float4*)(feat + (size_t)row * D_K + lane * 4);
    float ss = v.x * v.x + v.y * v.y + v.z * v.z + v.w * v.w;
    #pragma unroll
    for (int off = 1; off < 64; off <<= 1) ss += __shfl_xor(ss, off);
    float inv = 1.0f / fmaxf(sqrtf(ss), 1e-12f);
    ushort4 o;
    o.x = f2bf(v.x * inv); o.y = f2bf(v.y * inv);
    o.z = f2bf(v.z * inv); o.w = f2bf(v.w * inv);
    *(ushort4*)(fnorm + (size_t)row * D_K + lane * 4) = o;
}

// -------- Kernel 2: upper-triangular sim tiles — counted-vmcnt 4-buffer pipeline --------
// Evidence r0-r6: the 50us floor is invariant to waves/CU (16 vs 32) and LDS traffic
// (2x range); every variant shared __syncthreads() per chunk = vmcnt(0) full DMA drain,
// stalling all waves together. This version keeps loads IN FLIGHT across barriers:
//   iter kc: ISSUE(kc+2 -> buf[(kc+2)&3]); s_waitcnt vmcnt(4); s_barrier; COMPUTE(kc)
// Race-freedom with 4 buffers + 1 barrier/chunk:
//  - overwrite: ISSUE(kc+2) hits the buffer last read at COMPUTE(kc-2); every wave passed
//    barrier@kc-1, which is program-after COMPUTE(kc-2) -> all reads done.
//  - landing: vmcnt retires in order; a wave arrives at barrier@kc with <=4 outstanding
//    (chunks kc+1,kc+2) -> its chunk-kc loads landed; barrier certifies this for ALL waves.
// Tail: vmcnt(2) then vmcnt(0). Diag tiles (A only, 3% of work): same with halved counts.
// Geometry = r0's proven shape: 8 waves 2x4, 64x32/wave, acc[4][2] (~60 VGPR, no spill).
// KCH=32 staging swizzle = r4's HW-validated mapping (0 conflicts): thread t stages slot
// t&3 of row t>>2 holding global sub-chunk (t&3)^((t>>3)&3); read slot lhi^((l15>>1)&3).
// LDS: 4x8KB A + 4x8KB B + epilogue bufs ~ 71KB -> 2 blocks/CU (16 waves, the TLP knee).
// s_setprio(1) wraps each MFMA cluster (T5: pays once phases create role-split).
#define WAITV(N) asm volatile("s_waitcnt vmcnt(" #N ")" ::: "memory")
#define BARX() __builtin_amdgcn_s_barrier()

__global__ __launch_bounds__(NT, 4) void main_kernel(
        const unsigned short* __restrict__ fnorm, const int* __restrict__ labels,
        float2* __restrict__ G, float* __restrict__ gscal) {
    int bid = blockIdx.x;
    int b = (int)((sqrtf(8.0f * bid + 1.0f) - 1.0f) * 0.5f);
    while ((b + 1) * (b + 2) / 2 <= bid) ++b;
    while (b * (b + 1) / 2 > bid) --b;
    int a = bid - b * (b + 1) / 2;
    const int row0 = a * TILE, col0 = b * TILE;
    const bool diag = (a == b);

    __shared__ short As[4][TILE * KCH];         // 4 x 8 KB
    __shared__ short Bs[4][TILE * KCH];         // 4 x 8 KB
    __shared__ int Ls[2 * TILE];
    __shared__ float2 Rbuf[4 * TILE];           // [wn 0..3][128] row partials
    __shared__ float2 Cbuf[2 * TILE];           // [wm 0..1][128] col partials
    __shared__ int ghs[8];
    __shared__ float gps[8];

    const int tid = threadIdx.x;
    const int lane = tid & 63, wave = tid >> 6;
    const int wm = wave >> 2, wn = wave & 3;    // 2 (row) x 4 (col) waves; each 64x32
    const int l15 = lane & 15, lhi = lane >> 4;
    const short* fn = (const short*)fnorm;

    // staging (chunk = 128 rows x 64B = 8KB = 512 threads x 16B, one shot):
    // thread t: row t>>2, phys slot t&3, global sub-chunk (t&3)^((t>>3)&3); dest linear.
    const int rs = tid >> 2, cs = (tid & 3) ^ ((tid >> 3) & 3);
    const int uds = (tid & ~63) * 8;            // shorts; wave-uniform base, HW adds lane*16B
    const int abase = (row0 + rs) * D_K + cs * 8;   // 32-bit offsets: fnorm is 4MB
    const int bbase = (col0 + rs) * D_K + cs * 8;

    if (tid < 128) Ls[tid] = labels[row0 + tid];
    else if (tid < 256) Ls[tid] = labels[col0 + tid - 128];
    if (lane == 0) ghs[wave] = 0;

    // fragment LDS offsets (chunk-invariant): sub-chunk lhi at slot lhi^((row>>1)&3);
    // row bases are 0 mod 8 so the slot term reduces to l15.
    const int ch8 = (lhi ^ ((l15 >> 1) & 3)) * 8;
    int aoff[4], boff[2];
    #pragma unroll
    for (int mi = 0; mi < 4; mi++) aoff[mi] = (wm * 64 + mi * 16 + l15) * KCH + ch8;
    #pragma unroll
    for (int ni = 0; ni < 2; ni++) boff[ni] = (wn * 32 + ni * 16 + l15) * KCH + ch8;

    f32x4 acc[4][2];
    #pragma unroll
    for (int i = 0; i < 4; i++)
        #pragma unroll
        for (int j = 0; j < 2; j++) acc[i][j] = {0.f, 0.f, 0.f, 0.f};

#define ISSUE_AB(kc2) { gload_lds16(fn + abase + (kc2) * KCH, &As[(kc2) & 3][uds]); \
                        gload_lds16(fn + bbase + (kc2) * KCH, &Bs[(kc2) & 3][uds]); }
#define ISSUE_A(kc2)  { gload_lds16(fn + abase + (kc2) * KCH, &As[(kc2) & 3][uds]); }
#define COMPUTE(kc, BSRC) { \
    const short* Ap = As[(kc) & 3]; \
    const short* Bp = BSRC[(kc) & 3]; \
    short8 af[4], bfr[2]; \
    _Pragma("unroll") for (int mi = 0; mi < 4; mi++) af[mi] = *(const short8*)&Ap[aoff[mi]]; \
    _Pragma("unroll") for (int ni = 0; ni < 2; ni++) bfr[ni] = *(const short8*)&Bp[boff[ni]]; \
    __builtin_amdgcn_s_setprio(1); \
    _Pragma("unroll") for (int mi = 0; mi < 4; mi++) \
        _Pragma("unroll") for (int ni = 0; ni < 2; ni++) \
            acc[mi][ni] = __builtin_amdgcn_mfma_f32_16x16x32_bf16(af[mi], bfr[ni], acc[mi][ni], 0, 0, 0); \
    __builtin_amdgcn_s_setprio(0); }

    if (!diag) {
        ISSUE_AB(0) ISSUE_AB(1)
        ISSUE_AB(2) WAITV(4); BARX(); COMPUTE(0, Bs)
        ISSUE_AB(3) WAITV(4); BARX(); COMPUTE(1, Bs)
        ISSUE_AB(4) WAITV(4); BARX(); COMPUTE(2, Bs)
        ISSUE_AB(5) WAITV(4); BARX(); COMPUTE(3, Bs)
        ISSUE_AB(6) WAITV(4); BARX(); COMPUTE(4, Bs)
        ISSUE_AB(7) WAITV(4); BARX(); COMPUTE(5, Bs)
                    WAITV(2); BARX(); COMPUTE(6, Bs)
                    WAITV(0); BARX(); COMPUTE(7, Bs)
    } else {
        ISSUE_A(0) ISSUE_A(1)
        ISSUE_A(2) WAITV(2); BARX(); COMPUTE(0, As)
        ISSUE_A(3) WAITV(2); BARX(); COMPUTE(1, As)
        ISSUE_A(4) WAITV(2); BARX(); COMPUTE(2, As)
        ISSUE_A(5) WAITV(2); BARX(); COMPUTE(3, As)
        ISSUE_A(6) WAITV(2); BARX(); COMPUTE(4, As)
        ISSUE_A(7) WAITV(2); BARX(); COMPUTE(5, As)
                   WAITV(1); BARX(); COMPUTE(6, As)
                   WAITV(0); BARX(); COMPUTE(7, As)
    }

    // ---- Epilogue (r0-verified, bit-exact). C/D: col = lane&15, row = (lane>>4)*4+reg ----
    int lc[2], colg[2];
    #pragma unroll
    for (int ni = 0; ni < 2; ni++) {
        int c = wn * 32 + ni * 16 + l15;
        lc[ni] = Ls[128 + c];
        colg[ni] = col0 + c;
    }

    auto body = [&](auto DIAGC) {
        constexpr bool DIAG = decltype(DIAGC)::value;
        float cD[2] = {0.f, 0.f};
        float gp = 0.f;           // sum of positive-pair dots (this tile)
        bool anyhi = false;       // lane-mask predicate (SALU)

        #pragma unroll
        for (int mi = 0; mi < 4; mi++) {
            #pragma unroll
            for (int reg = 0; reg < 4; reg++) {
                int rloc = wm * 64 + mi * 16 + lhi * 4 + reg;
                int rowg = row0 + rloc;
                int lr = Ls[rloc];
                float d = 0.f;
                #pragma unroll
                for (int ni = 0; ni < 2; ni++) {
                    float dot = acc[mi][ni][reg];
                    float e = __builtin_exp2f((dot - 1.0f) * KEXP);   // e^(sim-20)
                    bool ns = !DIAG || (rowg != colg[ni]);   // off-diag: folds to true
                    float ev = ns ? e : 0.f;
                    d += ev; cD[ni] += ev;
                    bool ps = ns && (lr == lc[ni]);
                    gp += ps ? dot : 0.f;
                    anyhi = anyhi | (ps & (dot > 0.7f));
                }
                d = row_sum16(d);                  // VALU pipe, not LDS pipe
                if (l15 == 0) Rbuf[wn * 128 + rloc] = {d, 0.f};
            }
        }

        if (!DIAG) {
            #pragma unroll
            for (int ni = 0; ni < 2; ni++) {
                cD[ni] += __shfl_xor(cD[ni], 16);
                cD[ni] += __shfl_xor(cD[ni], 32);
            }
            if (lhi == 0) {
                #pragma unroll
                for (int ni = 0; ni < 2; ni++)
                    Cbuf[wm * 128 + wn * 32 + ni * 16 + l15] = {cD[ni], 0.f};
            }
        }

        gp = row_sum16(gp);
        gp += __shfl_xor(gp, 16);
        gp += __shfl_xor(gp, 32);
        if (lane == 0) gps[wave] = gp;

        // ---- Rare path: any high-similarity positive in this wave ----
        if (__any(anyhi)) {
            float cR[2] = {0.f, 0.f};
            int nhi = 0;
            #pragma unroll
            for (int mi = 0; mi < 4; mi++) {
                #pragma unroll
                for (int reg = 0; reg < 4; reg++) {
                    int rloc = wm * 64 + mi * 16 + lhi * 4 + reg;
                    int rowg = row0 + rloc;
                    int lr = Ls[rloc];
                    float rx = 0.f;
                    #pragma unroll
                    for (int ni = 0; ni < 2; ni++) {
                        float dot = acc[mi][ni][reg];
                        bool ns = !DIAG || (rowg != colg[ni]);
                        bool hi = ns && (lr == lc[ni]) && (dot > 0.7f);
                        float e = hi ? __builtin_exp2f((dot - 1.0f) * KEXP) : 0.f;
                        rx += e; cR[ni] += e; nhi += hi ? 1 : 0;
                    }
                    rx = row_sum16(rx);
                    if (l15 == 0) Rbuf[wn * 128 + rloc].y = rx;
                }
            }
            if (!DIAG) {
                #pragma unroll
                for (int ni = 0; ni < 2; ni++) {
                    cR[ni] += __shfl_xor(cR[ni], 16);
                    cR[ni] += __shfl_xor(cR[ni], 32);
                }
                if (lhi == 0) {
                    #pragma unroll
                    for (int ni = 0; ni < 2; ni++)
                        Cbuf[wm * 128 + wn * 32 + ni * 16 + l15].y = cR[ni];
                }
            }
            #pragma unroll
            for (int off = 1; off < 64; off <<= 1) nhi += __shfl_xor(nhi, off);
            if (lane == 0) ghs[wave] = nhi;
        }
    };
    if (diag) body(BoolC<true>{});
    else body(BoolC<false>{});
    __syncthreads();   // all Rbuf/Cbuf/gps/ghs writes visible

    if (tid < 128) {
        int r = tid;
        float2 a0 = Rbuf[r], a1 = Rbuf[128 + r], a2 = Rbuf[256 + r], a3 = Rbuf[384 + r];
        G[(size_t)b * B_N + row0 + r] = {a0.x + a1.x + a2.x + a3.x, a0.y + a1.y + a2.y + a3.y};
    } else if (tid < 256 && !diag) {
        int c = tid - 128;
        float2 a0 = Cbuf[c], a1 = Cbuf[128 + c];
        G[(size_t)a * B_N + col0 + c] = {a0.x + a1.x, a0.y + a1.y};
    }
    if (tid == 0) {
        float w = diag ? 1.0f : 2.0f;   // off-diag tile stands for (i,j) and (j,i)
        float gpt = gps[0] + gps[1] + gps[2] + gps[3] + gps[4] + gps[5] + gps[6] + gps[7];
        atomicAdd(&gscal[0], w * gpt);
        int tot = ghs[0] + ghs[1] + ghs[2] + ghs[3] + ghs[4] + ghs[5] + ghs[6] + ghs[7];
        if (tot > 0) atomicAdd(&gscal[1], w * (float)tot);
    }
}

// -------- Kernel 3: per-row reduction over 64 slots + last-block final assembly --------
__global__ void finalize_kernel(const float2* __restrict__ G, const int* __restrict__ labels,
                                const int* __restrict__ cnt, const float* __restrict__ gscal,
                                double* __restrict__ accum, unsigned int* __restrict__ done,
                                float* __restrict__ out) {
    int lane = threadIdx.x & 63, q = threadIdx.x >> 6;   // q = slot quarter
    int r = blockIdx.x * 64 + lane;
    float d = 0.f, rx = 0.f;
    #pragma unroll
    for (int s = 0; s < 16; ++s) {
        float2 g = G[(size_t)(q * 16 + s) * B_N + r];
        d += g.x; rx += g.y;
    }
    __shared__ float2 sh[4][64];
    sh[q][lane] = {d, rx};
    __syncthreads();
    if (threadIdx.x < 64) {
        int rr = blockIdx.x * 64 + threadIdx.x;
        float2 t0 = sh[0][threadIdx.x], t1 = sh[1][threadIdx.x];
        float2 t2 = sh[2][threadIdx.x], t3 = sh[3][threadIdx.x];
        float dd = t0.x + t1.x + t2.x + t3.x;
        float rr2 = t0.y + t1.y + t2.y + t3.y;
        float np = (float)(cnt[labels[rr]] - 1);
        float ld = logf(dd + 1e-12f) + 20.0f;             // log_denom (shift 20)
        double s1 = (double)np * (double)ld;
        double s2 = (double)np;
        double s3 = (rr2 > 0.f) ? (double)logf(rr2 + 1.0f) : 0.0;  // baseline=0: sim_max=20
        #pragma unroll
        for (int off = 1; off < 64; off <<= 1) {
            s1 += __shfl_xor(s1, off);
            s2 += __shfl_xor(s2, off);
            s3 += __shfl_xor(s3, off);
        }
        if (threadIdx.x == 0) {
            atomicAdd(&accum[0], s1);
            atomicAdd(&accum[1], s2);
            atomicAdd(&accum[2], s3);
            __threadfence();
            unsigned int tk = atomicAdd(done, 1u);
            if (tk == gridDim.x - 1) {           // last block assembles the scalar
                double a1 = atomicAdd(&accum[0], 0.0);
                double a2 = atomicAdd(&accum[1], 0.0);
                double a3 = atomicAdd(&accum[2], 0.0);
                double gp = (double)gscal[0];    // sum over ordered pos pairs of dot
                double gh = (double)gscal[1];    // count of high ordered pairs
                double scl = (a2 > 0.0) ? (a1 - 20.0 * gp) / fmax(a2, 1.0) : 0.0;
                double rel = (gh > 0.0) ? a3 / fmax(gh, 1.0) : 0.0;
                double tot = scl + rel;          // BETA = 1.0
                tot = fmin(fmax(tot, 0.0), 10.0);
                out[0] = (float)tot;
            }
        }
    }
}

extern "C" void kernel_launch(void* const* d_in, const int* in_sizes, int n_in,
                              void* d_out, int out_size, void* d_ws, size_t ws_size,
                              hipStream_t stream) {
    const float* feat = (const float*)d_in[0];
    const int* labels = (const int*)d_in[1];
    float* out = (float*)d_out;
    char* ws = (char*)d_ws;

    unsigned short* fnorm = (unsigned short*)(ws);                          // 4 MB
    float2* G          = (float2*)(ws + (size_t)4 * 1024 * 1024);           // 4 MB: [64][8192]
    int*    cnt        = (int*)(ws + (size_t)8 * 1024 * 1024);              // 400 B
    float*  gscal      = (float*)(ws + (size_t)8 * 1024 * 1024 + 1024);     // 8 B
    double* accum      = (double*)(ws + (size_t)8 * 1024 * 1024 + 2048);    // 24 B
    unsigned int* done = (unsigned int*)(ws + (size_t)8 * 1024 * 1024 + 3072); // 4 B

    prep_kernel<<<B_N / 4, 256, 0, stream>>>(feat, fnorm, labels, cnt, gscal, accum, done);
    main_kernel<<<NPAIR, NT, 0, stream>>>(fnorm, labels, G, gscal);
    finalize_kernel<<<B_N / 64, 256, 0, stream>>>(G, labels, cnt, gscal, accum, done, out);
    (void)in_sizes; (void)n_in; (void)out_size; (void)ws_size;
}